// Round 1
// baseline (477.077 us; speedup 1.0000x reference)
//
#include <hip/hip_runtime.h>
#include <hip/hip_bf16.h>

// ---------------------------------------------------------------------------
// BinarizedLayer: out[m,n] = sum_k x[m,k] * wbin[n,k] + bias[n]
//   wbin = (w < (upper-lower)) ? lower : upper,  upper=max(c1,c2), lower=min
// M=16384 (B*S), K=1024 (DIN), N=4096 (DOUT). fp32 in/out.
// Strategy: cast x & binarized w to bf16 in d_ws (needs ~40 MB), then
// m97-structure bf16 MFMA GEMM (128x128 tile, BK=32, global_load_lds 16B,
// ds_read_b128 fragments, 16x16x32 MFMA, bias fused in epilogue).
// ---------------------------------------------------------------------------

typedef __bf16 bf16x8 __attribute__((ext_vector_type(8)));
typedef float  f32x4  __attribute__((ext_vector_type(4)));

__device__ inline unsigned short f2bf(float f) {
    unsigned int u = __float_as_uint(f);
    // round-to-nearest-even on the bf16 boundary
    u += 0x7FFFu + ((u >> 16) & 1u);
    return (unsigned short)(u >> 16);
}

// ---- prep: x fp32 -> bf16 -------------------------------------------------
__global__ void cvt_x_kernel(const float4* __restrict__ in,
                             ushort4* __restrict__ out, int n4) {
    int stride = gridDim.x * blockDim.x;
    for (int i = blockIdx.x * blockDim.x + threadIdx.x; i < n4; i += stride) {
        float4 v = in[i];
        ushort4 o;
        o.x = f2bf(v.x); o.y = f2bf(v.y); o.z = f2bf(v.z); o.w = f2bf(v.w);
        out[i] = o;
    }
}

// ---- prep: binarize w and cast to bf16 ------------------------------------
__global__ void bin_w_kernel(const float4* __restrict__ w,
                             ushort4* __restrict__ out,
                             const float* __restrict__ c1,
                             const float* __restrict__ c2, int n4) {
    const float a = c1[0], b = c2[0];
    const float upper  = fmaxf(a, b);
    const float lower  = fminf(a, b);
    const float middle = upper - lower;   // threshold, exactly as reference
    const unsigned short lo16 = f2bf(lower);
    const unsigned short up16 = f2bf(upper);
    int stride = gridDim.x * blockDim.x;
    for (int i = blockIdx.x * blockDim.x + threadIdx.x; i < n4; i += stride) {
        float4 v = w[i];
        ushort4 o;
        o.x = (v.x < middle) ? lo16 : up16;
        o.y = (v.y < middle) ? lo16 : up16;
        o.z = (v.z < middle) ? lo16 : up16;
        o.w = (v.w < middle) ? lo16 : up16;
        out[i] = o;
    }
}

// ---- async 16B global -> LDS ----------------------------------------------
__device__ inline void async16(void* lds, const void* g) {
    __builtin_amdgcn_global_load_lds(
        (const __attribute__((address_space(1))) void*)g,
        (__attribute__((address_space(3))) void*)lds,
        16, 0, 0);
}

// ---- GEMM: C[m,n] = sum_k A[m,k]*B[n,k] + bias[n] (A,B bf16 bits, C fp32) -
// 128x128 tile, BK=32, 256 threads = 4 waves in 2x2, each wave 64x64 via
// 4x4 grid of 16x16x32 MFMA.
__global__ __launch_bounds__(256) void gemm_bin(
        const ushort* __restrict__ A,   // [M][K] bf16 bits
        const ushort* __restrict__ B,   // [N][K] bf16 bits
        const float*  __restrict__ bias,
        float* __restrict__ C,
        int M, int N, int K) {
    __shared__ ushort As[128 * 32];
    __shared__ ushort Bs[128 * 32];

    const int tid  = threadIdx.x;
    const int wave = tid >> 6;
    const int lane = tid & 63;

    const int bn = blockIdx.x;          // N-block (fastest varying)
    const int bm = blockIdx.y;          // M-block
    const int row0 = bm * 128;
    const int col0 = bn * 128;

    const int wm = (wave & 1) * 64;     // wave row offset in tile
    const int wn = (wave >> 1) * 64;    // wave col offset in tile

    f32x4 acc[4][4];
#pragma unroll
    for (int i = 0; i < 4; ++i)
#pragma unroll
        for (int j = 0; j < 4; ++j)
            acc[i][j] = (f32x4){0.f, 0.f, 0.f, 0.f};

    // staging: thread t covers LDS elements t*8 .. t*8+7 of a 64-row half-tile
    const int sr = tid >> 2;            // row 0..63 within half
    const int sc = (tid & 3) * 8;       // col in elements
    const ushort* a0 = A + (size_t)(row0 + sr) * K + sc;
    const ushort* a1 = A + (size_t)(row0 + 64 + sr) * K + sc;
    const ushort* b0 = B + (size_t)(col0 + sr) * K + sc;
    const ushort* b1 = B + (size_t)(col0 + 64 + sr) * K + sc;

    // wave-uniform LDS bases (lanes land at base + lane*16B)
    ushort* asd0 = &As[wave * 512];
    ushort* asd1 = &As[2048 + wave * 512];
    ushort* bsd0 = &Bs[wave * 512];
    ushort* bsd1 = &Bs[2048 + wave * 512];

    // fragment addressing: A[m = lane&15][k = (lane>>4)*8 + j]
    const int fr = lane & 15;
    const int fk = (lane >> 4) * 8;

    for (int k0 = 0; k0 < K; k0 += 32) {
        async16(asd0, a0 + k0);
        async16(asd1, a1 + k0);
        async16(bsd0, b0 + k0);
        async16(bsd1, b1 + k0);
        __syncthreads();   // compiler emits s_waitcnt vmcnt(0) before barrier

        bf16x8 af[4], bf[4];
#pragma unroll
        for (int i = 0; i < 4; ++i)
            af[i] = *(const bf16x8*)&As[(wm + i * 16 + fr) * 32 + fk];
#pragma unroll
        for (int j = 0; j < 4; ++j)
            bf[j] = *(const bf16x8*)&Bs[(wn + j * 16 + fr) * 32 + fk];

#pragma unroll
        for (int i = 0; i < 4; ++i)
#pragma unroll
            for (int j = 0; j < 4; ++j)
                acc[i][j] = __builtin_amdgcn_mfma_f32_16x16x32_bf16(
                    af[i], bf[j], acc[i][j], 0, 0, 0);

        __syncthreads();
    }

    // epilogue: C/D layout col=lane&15, row=(lane>>4)*4+reg
    const int er = (lane >> 4) * 4;
    const int ec = lane & 15;
#pragma unroll
    for (int j = 0; j < 4; ++j) {
        const int col = col0 + wn + j * 16 + ec;
        const float bz = bias[col];
#pragma unroll
        for (int i = 0; i < 4; ++i) {
            const size_t rbase = (size_t)(row0 + wm + i * 16 + er) * N + col;
#pragma unroll
            for (int r = 0; r < 4; ++r)
                C[rbase + (size_t)r * N] = acc[i][j][r] + bz;
        }
    }
}

extern "C" void kernel_launch(void* const* d_in, const int* in_sizes, int n_in,
                              void* d_out, int out_size, void* d_ws, size_t ws_size,
                              hipStream_t stream) {
    const float* x    = (const float*)d_in[0];   // [M][K]
    const float* w    = (const float*)d_in[1];   // [N][K]
    const float* c1   = (const float*)d_in[2];
    const float* c2   = (const float*)d_in[3];
    const float* bias = (const float*)d_in[4];   // [N]
    float* out = (float*)d_out;

    const int DOUT = in_sizes[4];                // 4096
    const int DIN  = in_sizes[1] / DOUT;         // 1024
    const int M    = in_sizes[0] / DIN;          // 16384
    const int N    = DOUT;
    const int K    = DIN;

    // workspace layout: x_bf16 (M*K ushort) then w_bf16 (N*K ushort) = 40 MB
    ushort* xb = (ushort*)d_ws;
    ushort* wb = xb + (size_t)M * K;

    const int nx4 = (M * K) / 4;
    const int nw4 = (N * K) / 4;
    cvt_x_kernel<<<4096, 256, 0, stream>>>((const float4*)x, (ushort4*)xb, nx4);
    bin_w_kernel<<<1024, 256, 0, stream>>>((const float4*)w, (ushort4*)wb, c1, c2, nw4);

    dim3 grid(N / 128, M / 128);   // (32, 128)
    gemm_bin<<<grid, 256, 0, stream>>>(xb, wb, bias, out, M, N, K);
}